// Round 16
// baseline (586.520 us; speedup 1.0000x reference)
//
#include <hip/hip_runtime.h>
#include <hip/hip_bf16.h>

typedef __hip_bfloat16 bf16;

#define N_NODES 100000
#define N_EDGES 1600000
#define IN_CH   128
#define ED_DIM  32
#define HEADS   4
#define C_OUT   32
#define HC      128   // HEADS * C_OUT
#define NEG_SLOPE 0.2f
#define SCAN_BLOCKS 98     // ceil(100000 / 1024)
#define PREP_BLOCKS 392    // ceil(100000 / 256) for fused prep+zero
#define NG_BLOCKS 3125     // N_NODES / 32; also 3125*512 == N_EDGES exactly
#define ES_BLOCKS 6250     // 25K waves * 16 quad-iterations = 400K quads

__device__ __forceinline__ float bf_lo(unsigned u) { return __uint_as_float(u << 16); }
__device__ __forceinline__ float bf_hi(unsigned u) { return __uint_as_float(u & 0xffff0000u); }
__device__ __forceinline__ unsigned short f2bf_rne(float f) {
    unsigned u = __float_as_uint(f);
    return (unsigned short)((u + 0x7fffu + ((u >> 16) & 1u)) >> 16);
}
__device__ __forceinline__ unsigned pack_bf2(float a, float b) {
    return ((unsigned)f2bf_rne(b) << 16) | f2bf_rne(a);
}
__device__ __forceinline__ float load_any(const void* p, int i, int isf32) {
    return isf32 ? ((const float*)p)[i]
                 : __uint_as_float(((unsigned)((const unsigned short*)p)[i]) << 16);
}

__global__ void report_err(unsigned short* out, float code) {
    if (threadIdx.x < 16) out[threadIdx.x] = f2bf_rne(code);
}

// ---------------------------------------------------------------------------
// prep_small: fused {dtype detect (block 0), small-tensor canonicalize
// (block 0), count[] zero (all blocks)}.
// Wa[h*32+d] = sum_c W_edge[d,h*32+c]*att_edge[h,c]
// ---------------------------------------------------------------------------
__global__ __launch_bounds__(256) void prep_small(
    const void* __restrict__ x,
    const void* __restrict__ W, const void* __restrict__ att_src,
    const void* __restrict__ att_dst, const void* __restrict__ W_edge,
    const void* __restrict__ att_edge, const void* __restrict__ gat_bias,
    const void* __restrict__ bias,
    int* __restrict__ flag,
    unsigned short* __restrict__ Wc, float* __restrict__ att_src_f,
    float* __restrict__ att_dst_f, float* __restrict__ gat_bias_f,
    float* __restrict__ bias_f, float* __restrict__ Wa,
    int* __restrict__ count) {

    int t = threadIdx.x;
    int gi = blockIdx.x * 256 + t;
    if (gi < N_NODES) count[gi] = 0;
    if (blockIdx.x != 0) return;

    // dtype detect (R4-verified: harness passes f32; kept for robustness)
    __shared__ int cnt;
    if (t == 0) cnt = 0;
    __syncthreads();
    unsigned xw = ((const unsigned*)x)[t];
    int ex = (xw >> 7) & 0xFF;
    if (ex >= 140) atomicAdd(&cnt, 1);
    __syncthreads();
    int isf32 = (cnt >= 32) ? 1 : 0;
    if (t == 0) *flag = isf32;

    for (int i = t; i < IN_CH * HC; i += 256)
        Wc[i] = f2bf_rne(load_any(W, i, isf32));
    if (t < 128) {
        att_src_f[t]  = load_any(att_src, t, isf32);
        att_dst_f[t]  = load_any(att_dst, t, isf32);
        gat_bias_f[t] = load_any(gat_bias, t, isf32);
    }
    if (t < 32) bias_f[t] = load_any(bias, t, isf32);
    if (t < 128) {
        int d = t & 31, h = t >> 5;
        float acc = 0.f;
        for (int c = 0; c < C_OUT; ++c)
            acc += load_any(W_edge, d * HC + h * C_OUT + c, isf32) *
                   load_any(att_edge, h * C_OUT + c, isf32);
        Wa[h * 32 + d] = acc;
    }
}

// ---------------------------------------------------------------------------
// xh = x @ W, 32 nodes/block, 16 acc/thread; fused a_src/a_dst epilogue
// + fused dst histogram WITH RANK CAPTURE (R14-measured good: atomics hide
// under GEMM VALU; rank write is a coalesced uint2; enables atomic-free
// edge_scatter).
// ---------------------------------------------------------------------------
__global__ __launch_bounds__(256) void node_gemm(
    const int* __restrict__ flag, const void* __restrict__ x,
    const int* __restrict__ ei,
    const unsigned short* __restrict__ Wc,
    const float* __restrict__ att_src_f, const float* __restrict__ att_dst_f,
    unsigned short* __restrict__ xh,
    float* __restrict__ a_src, float* __restrict__ a_dst,
    int* __restrict__ count, int* __restrict__ rank) {

    __shared__ unsigned short Wl[IN_CH * HC];   // 32 KB
    __shared__ float xl[32 * IN_CH];            // 16 KB

    int isf32 = *flag;
    int t = threadIdx.x;
    int node0 = blockIdx.x * 32;

    // fused dst histogram + rank: 3125 blocks * 256 threads * 2 = 1.6M edges
    {
        int p = blockIdx.x * 256 + t;
        const uint2* dst2 = (const uint2*)(ei + N_EDGES);
        uint2 d2 = dst2[p];
        int r0 = atomicAdd(&count[d2.x], 1);
        int r1 = atomicAdd(&count[d2.y], 1);
        ((int2*)rank)[p] = make_int2(r0, r1);
    }

    const uint4* Wg = (const uint4*)Wc;
    uint4* Wl4 = (uint4*)Wl;
#pragma unroll
    for (int k = 0; k < 8; ++k) Wl4[t + k * 256] = Wg[t + k * 256];

    if (isf32) {
        const float4* xg = (const float4*)((const float*)x + (size_t)node0 * IN_CH);
        float4* xl4 = (float4*)xl;
#pragma unroll
        for (int k = 0; k < 4; ++k) xl4[t + k * 256] = xg[t + k * 256];
    } else {
        const unsigned* xg = (const unsigned*)((const unsigned short*)x + (size_t)node0 * IN_CH);
#pragma unroll
        for (int k = 0; k < 8; ++k) {
            unsigned u = xg[t + k * 256];
            int f = 2 * (t + k * 256);
            xl[f]     = bf_lo(u);
            xl[f + 1] = bf_hi(u);
        }
    }
    __syncthreads();

    int q  = t & 31;
    int i0 = (t >> 5) * 4;
    int j4 = q * 4;
    float acc[16];
#pragma unroll
    for (int k = 0; k < 16; ++k) acc[k] = 0.f;

    const float* xr0 = xl + (i0 + 0) * IN_CH;
    const float* xr1 = xl + (i0 + 1) * IN_CH;
    const float* xr2 = xl + (i0 + 2) * IN_CH;
    const float* xr3 = xl + (i0 + 3) * IN_CH;

#pragma unroll 8
    for (int d = 0; d < IN_CH; ++d) {
        uint2 wb = *(const uint2*)(Wl + d * HC + j4);
        float w0 = bf_lo(wb.x), w1 = bf_hi(wb.x);
        float w2 = bf_lo(wb.y), w3 = bf_hi(wb.y);
        float x0 = xr0[d], x1 = xr1[d], x2 = xr2[d], x3 = xr3[d];
        acc[0]  += x0 * w0; acc[1]  += x0 * w1; acc[2]  += x0 * w2; acc[3]  += x0 * w3;
        acc[4]  += x1 * w0; acc[5]  += x1 * w1; acc[6]  += x1 * w2; acc[7]  += x1 * w3;
        acc[8]  += x2 * w0; acc[9]  += x2 * w1; acc[10] += x2 * w2; acc[11] += x2 * w3;
        acc[12] += x3 * w0; acc[13] += x3 * w1; acc[14] += x3 * w2; acc[15] += x3 * w3;
    }

    float4 sa = *(const float4*)(att_src_f + j4);
    float4 da = *(const float4*)(att_dst_f + j4);

#pragma unroll
    for (int k = 0; k < 4; ++k) {
        int node = node0 + i0 + k;
        float a0 = acc[4 * k], a1 = acc[4 * k + 1], a2 = acc[4 * k + 2], a3 = acc[4 * k + 3];
        *(uint2*)(xh + (size_t)node * HC + j4) =
            make_uint2(pack_bf2(a0, a1), pack_bf2(a2, a3));

        float ps = a0 * sa.x + a1 * sa.y + a2 * sa.z + a3 * sa.w;
        float pd = a0 * da.x + a1 * da.y + a2 * da.z + a3 * da.w;
        ps += __shfl_xor(ps, 1); ps += __shfl_xor(ps, 2); ps += __shfl_xor(ps, 4);
        pd += __shfl_xor(pd, 1); pd += __shfl_xor(pd, 2); pd += __shfl_xor(pd, 4);
        if ((q & 7) == 0) {
            int h = q >> 3;
            a_src[node * HEADS + h] = ps;
            a_dst[node * HEADS + h] = pd;
        }
    }
}

// ---------------------------------------------------------------------------
// exclusive prefix sum over count[] -> starts[]
// ---------------------------------------------------------------------------
__global__ __launch_bounds__(256) void scan_a(const int* __restrict__ count,
                                              int* __restrict__ starts,
                                              int* __restrict__ blockSums) {
    __shared__ int sd[256];
    int t = threadIdx.x;
    int base = blockIdx.x * 1024 + t * 4;
    int c0 = (base + 0 < N_NODES) ? count[base + 0] : 0;
    int c1 = (base + 1 < N_NODES) ? count[base + 1] : 0;
    int c2 = (base + 2 < N_NODES) ? count[base + 2] : 0;
    int c3 = (base + 3 < N_NODES) ? count[base + 3] : 0;
    int s = c0 + c1 + c2 + c3;
    sd[t] = s;
    __syncthreads();
    for (int off = 1; off < 256; off <<= 1) {
        int v = (t >= off) ? sd[t - off] : 0;
        __syncthreads();
        sd[t] += v;
        __syncthreads();
    }
    int excl = sd[t] - s;
    if (base + 0 < N_NODES) starts[base + 0] = excl;
    if (base + 1 < N_NODES) starts[base + 1] = excl + c0;
    if (base + 2 < N_NODES) starts[base + 2] = excl + c0 + c1;
    if (base + 3 < N_NODES) starts[base + 3] = excl + c0 + c1 + c2;
    if (t == 255) blockSums[blockIdx.x] = sd[255];
}

__global__ __launch_bounds__(128) void scan_b(int* __restrict__ blockSums) {
    __shared__ int sd[128];
    int t = threadIdx.x;
    int v = (t < SCAN_BLOCKS) ? blockSums[t] : 0;
    sd[t] = v;
    __syncthreads();
    for (int off = 1; off < 128; off <<= 1) {
        int u = (t >= off) ? sd[t - off] : 0;
        __syncthreads();
        sd[t] += u;
        __syncthreads();
    }
    if (t < SCAN_BLOCKS) blockSums[t] = sd[t] - v;   // exclusive
}

__global__ __launch_bounds__(256) void scan_c(int* __restrict__ starts,
                                              const int* __restrict__ blockSums) {
    int off = blockSums[blockIdx.x];
    int base = blockIdx.x * 1024 + threadIdx.x * 4;
#pragma unroll
    for (int k = 0; k < 4; ++k) {
        int idx = base + k;
        if (idx < N_NODES) starts[idx] += off;
    }
    if (blockIdx.x == 0 && threadIdx.x == 0) starts[N_NODES] = N_EDGES;
}

// ---------------------------------------------------------------------------
// edge_scatter v5 — WAVE-COOPERATIVE edges, atomic-free.
// R14 measured v4 (1 edge/thread) at 130 µs, VALUBusy 7%, HBM 29%, Occ 37%:
// latency-bound on each thread's serial {8 attr loads -> 64-FMA dot ->
// scattered write} chain; R13 proved fatter threads regress (VGPR/L2).
// v5: 16 lanes share one edge. A wave's 64 lanes fetch FOUR whole
// edge_attr rows in ONE coalesced 512 B instruction (8 B/lane); each lane
// does 8 FMA against a preloaded 8-reg Wa slice; 16-lane shfl_xor tree
// reduces the 4 head dots; lane l&3 handles head l&3's logit (a_src/a_dst
// reads broadcast-merge); lane 0 writes the record. Grid-stride: 16
// independent quad-iterations per wave -> compiler pipelines next-quad
// loads under the current reduce. No LDS, no barriers, ~32 VGPR.
// pos = starts[dn] + rank[e] (R14-validated atomic-free placement).
// Record: uint4{ src, w01, w23, 0 }.
// ---------------------------------------------------------------------------
__global__ __launch_bounds__(256) void edge_scatter(
    const int* __restrict__ flag,
    const int* __restrict__ ei, const void* __restrict__ edge_attr,
    const float* __restrict__ a_src, const float* __restrict__ a_dst,
    const float* __restrict__ Wa,
    const int* __restrict__ starts, const int* __restrict__ rank,
    uint4* __restrict__ perm4) {

    int t = threadIdx.x;
    int wv = t >> 6;               // wave 0..3
    int lane = t & 63;
    int g = lane >> 4;             // edge-of-quad 0..3
    int l = lane & 15;             // lane within group: dims 2l, 2l+1
    int isf32 = *flag;

    // per-lane Wa slice (constant across iterations): heads 0..3 x dims 2l,2l+1
    float wa00 = Wa[0 * 32 + 2 * l], wa01 = Wa[0 * 32 + 2 * l + 1];
    float wa10 = Wa[1 * 32 + 2 * l], wa11 = Wa[1 * 32 + 2 * l + 1];
    float wa20 = Wa[2 * 32 + 2 * l], wa21 = Wa[2 * 32 + 2 * l + 1];
    float wa30 = Wa[3 * 32 + 2 * l], wa31 = Wa[3 * 32 + 2 * l + 1];

    const int nquads = N_EDGES / 4;          // 400000
    const int qstride = ES_BLOCKS * 4;       // 25000 waves
    int h = l & 3;
    int gbase = lane & 48;                   // group base lane within wave

    for (int q = blockIdx.x * 4 + wv; q < nquads; q += qstride) {
        int e = q * 4 + g;
        int s  = ei[e];                      // 16 lanes same addr: broadcast
        int dn = ei[N_EDGES + e];
        int pos = starts[dn] + rank[e];

        float ea0, ea1;
        if (isf32) {
            float2 v = ((const float2*)edge_attr)[(size_t)e * 16 + l];
            ea0 = v.x; ea1 = v.y;
        } else {
            unsigned u = ((const unsigned*)edge_attr)[(size_t)e * 16 + l];
            ea0 = bf_lo(u); ea1 = bf_hi(u);
        }

        float p0 = ea0 * wa00 + ea1 * wa01;
        float p1 = ea0 * wa10 + ea1 * wa11;
        float p2 = ea0 * wa20 + ea1 * wa21;
        float p3 = ea0 * wa30 + ea1 * wa31;
        // reduce over the group's 16 lanes (lane bits 0..3)
        p0 += __shfl_xor(p0, 1); p0 += __shfl_xor(p0, 2);
        p0 += __shfl_xor(p0, 4); p0 += __shfl_xor(p0, 8);
        p1 += __shfl_xor(p1, 1); p1 += __shfl_xor(p1, 2);
        p1 += __shfl_xor(p1, 4); p1 += __shfl_xor(p1, 8);
        p2 += __shfl_xor(p2, 1); p2 += __shfl_xor(p2, 2);
        p2 += __shfl_xor(p2, 4); p2 += __shfl_xor(p2, 8);
        p3 += __shfl_xor(p3, 1); p3 += __shfl_xor(p3, 2);
        p3 += __shfl_xor(p3, 4); p3 += __shfl_xor(p3, 8);

        // head-split epilogue: lane handles head h = l&3 (cndmask select,
        // not dynamic indexing); a_src/a_dst reads broadcast-merge (4 addrs
        // per group, each read by 4 lanes).
        float ae = (h == 0) ? p0 : (h == 1) ? p1 : (h == 2) ? p2 : p3;
        float lg = a_src[4 * s + h] + a_dst[4 * dn + h] + ae;
        lg = (lg >= 0.f) ? lg : NEG_SLOPE * lg;
        // logits O(1): unnormalized exp safe; ratio is exact softmax
        float wgt = __expf(lg);

        float w1v = __shfl(wgt, gbase + 1);
        float w2v = __shfl(wgt, gbase + 2);
        float w3v = __shfl(wgt, gbase + 3);
        if (l == 0) {
            perm4[pos] = make_uint4((unsigned)s, pack_bf2(wgt, w1v),
                                    pack_bf2(w2v, w3v), 0u);
        }
    }
}

// ---------------------------------------------------------------------------
// gather v6 (R4/R8/R14-measured): wave per node, FOUR edges per inner
// iteration, single-hop LDS staging of uint4{src,w01,w23,-}.
// ---------------------------------------------------------------------------
__global__ __launch_bounds__(256) void gather(
    const int* __restrict__ flag,
    const int* __restrict__ starts, const uint4* __restrict__ perm4,
    const unsigned short* __restrict__ xh,
    const float* __restrict__ gat_bias_f, const float* __restrict__ bias_f,
    void* __restrict__ out) {

    __shared__ uint4 sR[4][64];   // 4 KB

    int t = threadIdx.x;
    int w = t >> 6, lane = t & 63;
    int quarter = lane >> 4;       // which edge of the quad this lane serves
    int l = lane & 15;             // channel octet: channels 8l..8l+7
    int h = l >> 2;                // head = (8l)>>5
    int n = blockIdx.x * 4 + w;
    if (n >= N_NODES) return;
    int isf32 = *flag;

    int st = starts[n], en = starts[n + 1];
    float f0 = 0.f, f1 = 0.f, f2 = 0.f, f3 = 0.f;
    float f4 = 0.f, f5 = 0.f, f6 = 0.f, f7 = 0.f, wsum = 0.f;

    for (int base = st; base < en; base += 64) {
        int cnt = en - base;
        if (cnt > 64) cnt = 64;
        __builtin_amdgcn_wave_barrier();
        if (lane < cnt) sR[w][lane] = perm4[base + lane];
        __builtin_amdgcn_wave_barrier();
#pragma unroll 4
        for (int jj = 0; jj < cnt; jj += 4) {
            int j = jj + quarter;
            int valid = (j < cnt);
            int jc = valid ? j : jj;
            uint4 r = sR[w][jc];
            int s = (int)r.x;
            unsigned hw = (h & 2) ? r.z : r.y;
            float wt = (h & 1) ? bf_hi(hw) : bf_lo(hw);
            wt = valid ? wt : 0.f;
            uint4 xv = *(const uint4*)(xh + ((size_t)s << 7) + 8 * l);
            f0 += wt * bf_lo(xv.x);
            f1 += wt * bf_hi(xv.x);
            f2 += wt * bf_lo(xv.y);
            f3 += wt * bf_hi(xv.y);
            f4 += wt * bf_lo(xv.z);
            f5 += wt * bf_hi(xv.z);
            f6 += wt * bf_lo(xv.w);
            f7 += wt * bf_hi(xv.w);
            wsum += wt;
        }
    }

    // combine the four quarters (lane bits 4,5 = quarter bits)
    f0 += __shfl_xor(f0, 16); f0 += __shfl_xor(f0, 32);
    f1 += __shfl_xor(f1, 16); f1 += __shfl_xor(f1, 32);
    f2 += __shfl_xor(f2, 16); f2 += __shfl_xor(f2, 32);
    f3 += __shfl_xor(f3, 16); f3 += __shfl_xor(f3, 32);
    f4 += __shfl_xor(f4, 16); f4 += __shfl_xor(f4, 32);
    f5 += __shfl_xor(f5, 16); f5 += __shfl_xor(f5, 32);
    f6 += __shfl_xor(f6, 16); f6 += __shfl_xor(f6, 32);
    f7 += __shfl_xor(f7, 16); f7 += __shfl_xor(f7, 32);
    wsum += __shfl_xor(wsum, 16); wsum += __shfl_xor(wsum, 32);

    float inv = (wsum > 0.f) ? 1.f / wsum : 0.f;
    int cg = 8 * l;
    float v0 = f0 * inv + gat_bias_f[cg];
    float v1 = f1 * inv + gat_bias_f[cg + 1];
    float v2 = f2 * inv + gat_bias_f[cg + 2];
    float v3 = f3 * inv + gat_bias_f[cg + 3];
    float v4 = f4 * inv + gat_bias_f[cg + 4];
    float v5 = f5 * inv + gat_bias_f[cg + 5];
    float v6 = f6 * inv + gat_bias_f[cg + 6];
    float v7 = f7 * inv + gat_bias_f[cg + 7];
    // reduce over 4 heads: head bits live in lane bits 2,3
    v0 += __shfl_xor(v0, 4); v0 += __shfl_xor(v0, 8);
    v1 += __shfl_xor(v1, 4); v1 += __shfl_xor(v1, 8);
    v2 += __shfl_xor(v2, 4); v2 += __shfl_xor(v2, 8);
    v3 += __shfl_xor(v3, 4); v3 += __shfl_xor(v3, 8);
    v4 += __shfl_xor(v4, 4); v4 += __shfl_xor(v4, 8);
    v5 += __shfl_xor(v5, 4); v5 += __shfl_xor(v5, 8);
    v6 += __shfl_xor(v6, 4); v6 += __shfl_xor(v6, 8);
    v7 += __shfl_xor(v7, 4); v7 += __shfl_xor(v7, 8);

    if (lane < 4) {
        int c = 8 * lane;
        float o0 = fmaxf(v0 * 0.25f + bias_f[c],     0.f);
        float o1 = fmaxf(v1 * 0.25f + bias_f[c + 1], 0.f);
        float o2 = fmaxf(v2 * 0.25f + bias_f[c + 2], 0.f);
        float o3 = fmaxf(v3 * 0.25f + bias_f[c + 3], 0.f);
        float o4 = fmaxf(v4 * 0.25f + bias_f[c + 4], 0.f);
        float o5 = fmaxf(v5 * 0.25f + bias_f[c + 5], 0.f);
        float o6 = fmaxf(v6 * 0.25f + bias_f[c + 6], 0.f);
        float o7 = fmaxf(v7 * 0.25f + bias_f[c + 7], 0.f);
        if (isf32) {
            float* op = (float*)out + (size_t)n * C_OUT + c;
            *(float4*)(op)     = make_float4(o0, o1, o2, o3);
            *(float4*)(op + 4) = make_float4(o4, o5, o6, o7);
        } else {
            unsigned p0 = ((unsigned)f2bf_rne(o1) << 16) | f2bf_rne(o0);
            unsigned p1 = ((unsigned)f2bf_rne(o3) << 16) | f2bf_rne(o2);
            unsigned p2 = ((unsigned)f2bf_rne(o5) << 16) | f2bf_rne(o4);
            unsigned p3 = ((unsigned)f2bf_rne(o7) << 16) | f2bf_rne(o6);
            *(uint4*)((unsigned short*)out + (size_t)n * C_OUT + c) =
                make_uint4(p0, p1, p2, p3);
        }
    }
}

// ---------------------------------------------------------------------------
extern "C" void kernel_launch(void* const* d_in, const int* in_sizes, int n_in,
                              void* d_out, int out_size, void* d_ws, size_t ws_size,
                              hipStream_t stream) {
    const void* x         = d_in[0];
    const int*  ei        = (const int*)d_in[1];
    const void* edge_attr = d_in[2];
    const void* W         = d_in[3];
    const void* att_src   = d_in[4];
    const void* att_dst   = d_in[5];
    const void* W_edge    = d_in[6];
    const void* att_edge  = d_in[7];
    const void* gat_bias  = d_in[8];
    const void* bias      = d_in[9];

    char* ws = (char*)d_ws;
    size_t off = 0;
    auto align256 = [](size_t v) { return (v + 255) & ~(size_t)255; };

    unsigned short* xh = (unsigned short*)(ws + off);
    off = align256(off + (size_t)N_NODES * HC * sizeof(unsigned short));  // 25.6 MB
    float* a_src_w = (float*)(ws + off);
    off = align256(off + (size_t)N_NODES * HEADS * sizeof(float));
    float* a_dst_w = (float*)(ws + off);
    off = align256(off + (size_t)N_NODES * HEADS * sizeof(float));
    int* count = (int*)(ws + off);
    off = align256(off + (size_t)N_NODES * sizeof(int));
    int* starts = (int*)(ws + off);
    off = align256(off + (size_t)(N_NODES + 1) * sizeof(int));
    int* rank = (int*)(ws + off);
    off = align256(off + (size_t)N_EDGES * sizeof(int));                  // 6.4 MB
    int* blockSums = (int*)(ws + off);
    off = align256(off + (size_t)SCAN_BLOCKS * sizeof(int));
    uint4* perm4 = (uint4*)(ws + off);
    off = align256(off + (size_t)N_EDGES * sizeof(uint4));                // 25.6 MB
    float* Wa = (float*)(ws + off);
    off = align256(off + 128 * sizeof(float));
    unsigned short* Wc = (unsigned short*)(ws + off);
    off = align256(off + (size_t)IN_CH * HC * sizeof(unsigned short));
    float* att_src_f = (float*)(ws + off);
    off = align256(off + 128 * sizeof(float));
    float* att_dst_f = (float*)(ws + off);
    off = align256(off + 128 * sizeof(float));
    float* gat_bias_f = (float*)(ws + off);
    off = align256(off + 128 * sizeof(float));
    float* bias_f = (float*)(ws + off);
    off = align256(off + 32 * sizeof(float));
    int* dflag = (int*)(ws + off);
    off = align256(off + sizeof(int));
    size_t need = off;

    if (ws_size < need) {
        report_err<<<1, 64, 0, stream>>>((unsigned short*)d_out, 1500.0f);
        return;
    }

    (void)hipGetLastError();

    prep_small<<<PREP_BLOCKS, 256, 0, stream>>>(x, W, att_src, att_dst,
                                                W_edge, att_edge, gat_bias, bias,
                                                dflag, Wc, att_src_f, att_dst_f,
                                                gat_bias_f, bias_f, Wa, count);
    node_gemm<<<NG_BLOCKS, 256, 0, stream>>>(dflag, x, ei, Wc, att_src_f,
                                             att_dst_f, xh, a_src_w, a_dst_w,
                                             count, rank);
    scan_a<<<SCAN_BLOCKS, 256, 0, stream>>>(count, starts, blockSums);
    scan_b<<<1, 128, 0, stream>>>(blockSums);
    scan_c<<<SCAN_BLOCKS, 256, 0, stream>>>(starts, blockSums);
    edge_scatter<<<ES_BLOCKS, 256, 0, stream>>>(dflag, ei, edge_attr,
                                                a_src_w, a_dst_w, Wa,
                                                starts, rank, perm4);
    gather<<<N_NODES / 4, 256, 0, stream>>>(dflag, starts, perm4,
                                            xh, gat_bias_f, bias_f, d_out);

    hipError_t e = hipGetLastError();
    if (e != hipSuccess) {
        report_err<<<1, 64, 0, stream>>>((unsigned short*)d_out,
                                         1000.0f + (float)(int)e);
    }
}

// Round 17
// 546.353 us; speedup vs baseline: 1.0735x; 1.0735x over previous
//
#include <hip/hip_runtime.h>
#include <hip/hip_bf16.h>

typedef __hip_bfloat16 bf16;

#define N_NODES 100000
#define N_EDGES 1600000
#define IN_CH   128
#define ED_DIM  32
#define HEADS   4
#define C_OUT   32
#define HC      128   // HEADS * C_OUT
#define NEG_SLOPE 0.2f
#define SCAN_BLOCKS 98     // ceil(100000 / 1024)
#define PREP_BLOCKS 392    // ceil(100000 / 256) for fused prep+zero
#define NG_BLOCKS 3125     // N_NODES / 32; also 3125*512 == N_EDGES exactly
#define ES_BLOCKS 2048     // persistent: 8 blocks/CU x 256 CUs = 32 waves/CU

__device__ __forceinline__ float bf_lo(unsigned u) { return __uint_as_float(u << 16); }
__device__ __forceinline__ float bf_hi(unsigned u) { return __uint_as_float(u & 0xffff0000u); }
__device__ __forceinline__ unsigned short f2bf_rne(float f) {
    unsigned u = __float_as_uint(f);
    return (unsigned short)((u + 0x7fffu + ((u >> 16) & 1u)) >> 16);
}
__device__ __forceinline__ unsigned pack_bf2(float a, float b) {
    return ((unsigned)f2bf_rne(b) << 16) | f2bf_rne(a);
}
__device__ __forceinline__ float load_any(const void* p, int i, int isf32) {
    return isf32 ? ((const float*)p)[i]
                 : __uint_as_float(((unsigned)((const unsigned short*)p)[i]) << 16);
}

__global__ void report_err(unsigned short* out, float code) {
    if (threadIdx.x < 16) out[threadIdx.x] = f2bf_rne(code);
}

// ---------------------------------------------------------------------------
// prep_small: fused {dtype detect (block 0), small-tensor canonicalize
// (block 0), count[] zero (all blocks)}.
// Wa[h*32+d] = sum_c W_edge[d,h*32+c]*att_edge[h,c]
// ---------------------------------------------------------------------------
__global__ __launch_bounds__(256) void prep_small(
    const void* __restrict__ x,
    const void* __restrict__ W, const void* __restrict__ att_src,
    const void* __restrict__ att_dst, const void* __restrict__ W_edge,
    const void* __restrict__ att_edge, const void* __restrict__ gat_bias,
    const void* __restrict__ bias,
    int* __restrict__ flag,
    unsigned short* __restrict__ Wc, float* __restrict__ att_src_f,
    float* __restrict__ att_dst_f, float* __restrict__ gat_bias_f,
    float* __restrict__ bias_f, float* __restrict__ Wa,
    int* __restrict__ count) {

    int t = threadIdx.x;
    int gi = blockIdx.x * 256 + t;
    if (gi < N_NODES) count[gi] = 0;
    if (blockIdx.x != 0) return;

    // dtype detect (R4-verified: harness passes f32; kept for robustness)
    __shared__ int cnt;
    if (t == 0) cnt = 0;
    __syncthreads();
    unsigned xw = ((const unsigned*)x)[t];
    int ex = (xw >> 7) & 0xFF;
    if (ex >= 140) atomicAdd(&cnt, 1);
    __syncthreads();
    int isf32 = (cnt >= 32) ? 1 : 0;
    if (t == 0) *flag = isf32;

    for (int i = t; i < IN_CH * HC; i += 256)
        Wc[i] = f2bf_rne(load_any(W, i, isf32));
    if (t < 128) {
        att_src_f[t]  = load_any(att_src, t, isf32);
        att_dst_f[t]  = load_any(att_dst, t, isf32);
        gat_bias_f[t] = load_any(gat_bias, t, isf32);
    }
    if (t < 32) bias_f[t] = load_any(bias, t, isf32);
    if (t < 128) {
        int d = t & 31, h = t >> 5;
        float acc = 0.f;
        for (int c = 0; c < C_OUT; ++c)
            acc += load_any(W_edge, d * HC + h * C_OUT + c, isf32) *
                   load_any(att_edge, h * C_OUT + c, isf32);
        Wa[h * 32 + d] = acc;
    }
}

// ---------------------------------------------------------------------------
// xh = x @ W, 32 nodes/block, 16 acc/thread; fused a_src/a_dst epilogue
// + fused dst histogram WITH RANK CAPTURE (R14-measured good: atomics hide
// under GEMM VALU; rank write is a coalesced uint2; enables atomic-free
// edge_scatter).
// ---------------------------------------------------------------------------
__global__ __launch_bounds__(256) void node_gemm(
    const int* __restrict__ flag, const void* __restrict__ x,
    const int* __restrict__ ei,
    const unsigned short* __restrict__ Wc,
    const float* __restrict__ att_src_f, const float* __restrict__ att_dst_f,
    unsigned short* __restrict__ xh,
    float* __restrict__ a_src, float* __restrict__ a_dst,
    int* __restrict__ count, int* __restrict__ rank) {

    __shared__ unsigned short Wl[IN_CH * HC];   // 32 KB
    __shared__ float xl[32 * IN_CH];            // 16 KB

    int isf32 = *flag;
    int t = threadIdx.x;
    int node0 = blockIdx.x * 32;

    // fused dst histogram + rank: 3125 blocks * 256 threads * 2 = 1.6M edges
    {
        int p = blockIdx.x * 256 + t;
        const uint2* dst2 = (const uint2*)(ei + N_EDGES);
        uint2 d2 = dst2[p];
        int r0 = atomicAdd(&count[d2.x], 1);
        int r1 = atomicAdd(&count[d2.y], 1);
        ((int2*)rank)[p] = make_int2(r0, r1);
    }

    const uint4* Wg = (const uint4*)Wc;
    uint4* Wl4 = (uint4*)Wl;
#pragma unroll
    for (int k = 0; k < 8; ++k) Wl4[t + k * 256] = Wg[t + k * 256];

    if (isf32) {
        const float4* xg = (const float4*)((const float*)x + (size_t)node0 * IN_CH);
        float4* xl4 = (float4*)xl;
#pragma unroll
        for (int k = 0; k < 4; ++k) xl4[t + k * 256] = xg[t + k * 256];
    } else {
        const unsigned* xg = (const unsigned*)((const unsigned short*)x + (size_t)node0 * IN_CH);
#pragma unroll
        for (int k = 0; k < 8; ++k) {
            unsigned u = xg[t + k * 256];
            int f = 2 * (t + k * 256);
            xl[f]     = bf_lo(u);
            xl[f + 1] = bf_hi(u);
        }
    }
    __syncthreads();

    int q  = t & 31;
    int i0 = (t >> 5) * 4;
    int j4 = q * 4;
    float acc[16];
#pragma unroll
    for (int k = 0; k < 16; ++k) acc[k] = 0.f;

    const float* xr0 = xl + (i0 + 0) * IN_CH;
    const float* xr1 = xl + (i0 + 1) * IN_CH;
    const float* xr2 = xl + (i0 + 2) * IN_CH;
    const float* xr3 = xl + (i0 + 3) * IN_CH;

#pragma unroll 8
    for (int d = 0; d < IN_CH; ++d) {
        uint2 wb = *(const uint2*)(Wl + d * HC + j4);
        float w0 = bf_lo(wb.x), w1 = bf_hi(wb.x);
        float w2 = bf_lo(wb.y), w3 = bf_hi(wb.y);
        float x0 = xr0[d], x1 = xr1[d], x2 = xr2[d], x3 = xr3[d];
        acc[0]  += x0 * w0; acc[1]  += x0 * w1; acc[2]  += x0 * w2; acc[3]  += x0 * w3;
        acc[4]  += x1 * w0; acc[5]  += x1 * w1; acc[6]  += x1 * w2; acc[7]  += x1 * w3;
        acc[8]  += x2 * w0; acc[9]  += x2 * w1; acc[10] += x2 * w2; acc[11] += x2 * w3;
        acc[12] += x3 * w0; acc[13] += x3 * w1; acc[14] += x3 * w2; acc[15] += x3 * w3;
    }

    float4 sa = *(const float4*)(att_src_f + j4);
    float4 da = *(const float4*)(att_dst_f + j4);

#pragma unroll
    for (int k = 0; k < 4; ++k) {
        int node = node0 + i0 + k;
        float a0 = acc[4 * k], a1 = acc[4 * k + 1], a2 = acc[4 * k + 2], a3 = acc[4 * k + 3];
        *(uint2*)(xh + (size_t)node * HC + j4) =
            make_uint2(pack_bf2(a0, a1), pack_bf2(a2, a3));

        float ps = a0 * sa.x + a1 * sa.y + a2 * sa.z + a3 * sa.w;
        float pd = a0 * da.x + a1 * da.y + a2 * da.z + a3 * da.w;
        ps += __shfl_xor(ps, 1); ps += __shfl_xor(ps, 2); ps += __shfl_xor(ps, 4);
        pd += __shfl_xor(pd, 1); pd += __shfl_xor(pd, 2); pd += __shfl_xor(pd, 4);
        if ((q & 7) == 0) {
            int h = q >> 3;
            a_src[node * HEADS + h] = ps;
            a_dst[node * HEADS + h] = pd;
        }
    }
}

// ---------------------------------------------------------------------------
// exclusive prefix sum over count[] -> starts[]
// ---------------------------------------------------------------------------
__global__ __launch_bounds__(256) void scan_a(const int* __restrict__ count,
                                              int* __restrict__ starts,
                                              int* __restrict__ blockSums) {
    __shared__ int sd[256];
    int t = threadIdx.x;
    int base = blockIdx.x * 1024 + t * 4;
    int c0 = (base + 0 < N_NODES) ? count[base + 0] : 0;
    int c1 = (base + 1 < N_NODES) ? count[base + 1] : 0;
    int c2 = (base + 2 < N_NODES) ? count[base + 2] : 0;
    int c3 = (base + 3 < N_NODES) ? count[base + 3] : 0;
    int s = c0 + c1 + c2 + c3;
    sd[t] = s;
    __syncthreads();
    for (int off = 1; off < 256; off <<= 1) {
        int v = (t >= off) ? sd[t - off] : 0;
        __syncthreads();
        sd[t] += v;
        __syncthreads();
    }
    int excl = sd[t] - s;
    if (base + 0 < N_NODES) starts[base + 0] = excl;
    if (base + 1 < N_NODES) starts[base + 1] = excl + c0;
    if (base + 2 < N_NODES) starts[base + 2] = excl + c0 + c1;
    if (base + 3 < N_NODES) starts[base + 3] = excl + c0 + c1 + c2;
    if (t == 255) blockSums[blockIdx.x] = sd[255];
}

__global__ __launch_bounds__(128) void scan_b(int* __restrict__ blockSums) {
    __shared__ int sd[128];
    int t = threadIdx.x;
    int v = (t < SCAN_BLOCKS) ? blockSums[t] : 0;
    sd[t] = v;
    __syncthreads();
    for (int off = 1; off < 128; off <<= 1) {
        int u = (t >= off) ? sd[t - off] : 0;
        __syncthreads();
        sd[t] += u;
        __syncthreads();
    }
    if (t < SCAN_BLOCKS) blockSums[t] = sd[t] - v;   // exclusive
}

__global__ __launch_bounds__(256) void scan_c(int* __restrict__ starts,
                                              const int* __restrict__ blockSums) {
    int off = blockSums[blockIdx.x];
    int base = blockIdx.x * 1024 + threadIdx.x * 4;
#pragma unroll
    for (int k = 0; k < 4; ++k) {
        int idx = base + k;
        if (idx < N_NODES) starts[idx] += off;
    }
    if (blockIdx.x == 0 && threadIdx.x == 0) starts[N_NODES] = N_EDGES;
}

// ---------------------------------------------------------------------------
// edge_scatter v6 — v4's measured-good body (130 µs: dense 1-edge/thread,
// atomic-free pos = starts[dn] + rank[e]) wrapped in a PERSISTENT
// grid-stride loop. R14 counters showed Occ 37% at only 56 VGPR -> not
// register-limited; 6250 short-lived blocks suggest dispatch/drain churn.
// 2048 blocks = exactly 8 blocks/CU = 32 waves/CU (8 waves/SIMD x 56 VGPR
// = 448 <= 512 budget); each thread loops ~3 edges. Body unchanged.
// (R16 lesson: wave-cooperative shuffle reduce QUADRUPLED VALU work and
// regressed to 169 µs — shuffles are not free; keep the serial dot.)
// Record: uint4{ src, w01, w23, 0 }.
// ---------------------------------------------------------------------------
__global__ __launch_bounds__(256) void edge_scatter(
    const int* __restrict__ flag,
    const int* __restrict__ ei, const void* __restrict__ edge_attr,
    const float* __restrict__ a_src, const float* __restrict__ a_dst,
    const float* __restrict__ Wa,
    const int* __restrict__ starts, const int* __restrict__ rank,
    uint4* __restrict__ perm4) {

    __shared__ float WaL[128];
    int t = threadIdx.x;
    if (t < 128) WaL[t] = Wa[t];
    __syncthreads();

    int isf32 = *flag;

    for (int e = blockIdx.x * 256 + t; e < N_EDGES; e += ES_BLOCKS * 256) {
        int s  = ei[e];
        int dn = ei[N_EDGES + e];
        int pos = starts[dn] + rank[e];   // no atomic; hoists above the dot

        float ae0 = 0.f, ae1 = 0.f, ae2 = 0.f, ae3 = 0.f;
        if (isf32) {
            const float4* ea = (const float4*)((const float*)edge_attr + (size_t)e * ED_DIM);
#pragma unroll
            for (int k = 0; k < 8; ++k) {
                float4 v = ea[k];
                int d = 4 * k;
                ae0 += v.x * WaL[d] + v.y * WaL[d + 1] + v.z * WaL[d + 2] + v.w * WaL[d + 3];
                ae1 += v.x * WaL[32 + d] + v.y * WaL[33 + d] + v.z * WaL[34 + d] + v.w * WaL[35 + d];
                ae2 += v.x * WaL[64 + d] + v.y * WaL[65 + d] + v.z * WaL[66 + d] + v.w * WaL[67 + d];
                ae3 += v.x * WaL[96 + d] + v.y * WaL[97 + d] + v.z * WaL[98 + d] + v.w * WaL[99 + d];
            }
        } else {
            const uint4* ea = (const uint4*)((const unsigned short*)edge_attr + (size_t)e * ED_DIM);
#pragma unroll
            for (int k = 0; k < 4; ++k) {
                uint4 v = ea[k];
                float g0 = bf_lo(v.x), g1 = bf_hi(v.x), g2 = bf_lo(v.y), g3 = bf_hi(v.y);
                float g4 = bf_lo(v.z), g5 = bf_hi(v.z), g6 = bf_lo(v.w), g7 = bf_hi(v.w);
                int d = 8 * k;
                ae0 += g0*WaL[d] + g1*WaL[d+1] + g2*WaL[d+2] + g3*WaL[d+3]
                     + g4*WaL[d+4] + g5*WaL[d+5] + g6*WaL[d+6] + g7*WaL[d+7];
                ae1 += g0*WaL[32+d] + g1*WaL[33+d] + g2*WaL[34+d] + g3*WaL[35+d]
                     + g4*WaL[36+d] + g5*WaL[37+d] + g6*WaL[38+d] + g7*WaL[39+d];
                ae2 += g0*WaL[64+d] + g1*WaL[65+d] + g2*WaL[66+d] + g3*WaL[67+d]
                     + g4*WaL[68+d] + g5*WaL[69+d] + g6*WaL[70+d] + g7*WaL[71+d];
                ae3 += g0*WaL[96+d] + g1*WaL[97+d] + g2*WaL[98+d] + g3*WaL[99+d]
                     + g4*WaL[100+d] + g5*WaL[101+d] + g6*WaL[102+d] + g7*WaL[103+d];
            }
        }

        float4 as = *(const float4*)(a_src + (size_t)s * 4);
        float4 ad = *(const float4*)(a_dst + (size_t)dn * 4);
        float l0 = as.x + ad.x + ae0;
        float l1 = as.y + ad.y + ae1;
        float l2 = as.z + ad.z + ae2;
        float l3 = as.w + ad.w + ae3;
        l0 = (l0 >= 0.f) ? l0 : NEG_SLOPE * l0;
        l1 = (l1 >= 0.f) ? l1 : NEG_SLOPE * l1;
        l2 = (l2 >= 0.f) ? l2 : NEG_SLOPE * l2;
        l3 = (l3 >= 0.f) ? l3 : NEG_SLOPE * l3;
        // logits O(1): unnormalized exp safe; ratio is exact softmax
        float w0 = __expf(l0), w1 = __expf(l1), w2 = __expf(l2), w3 = __expf(l3);

        perm4[pos] = make_uint4((unsigned)s, pack_bf2(w0, w1), pack_bf2(w2, w3), 0u);
    }
}

// ---------------------------------------------------------------------------
// gather v6 (R4/R8/R14-measured): wave per node, FOUR edges per inner
// iteration, single-hop LDS staging of uint4{src,w01,w23,-}.
// ---------------------------------------------------------------------------
__global__ __launch_bounds__(256) void gather(
    const int* __restrict__ flag,
    const int* __restrict__ starts, const uint4* __restrict__ perm4,
    const unsigned short* __restrict__ xh,
    const float* __restrict__ gat_bias_f, const float* __restrict__ bias_f,
    void* __restrict__ out) {

    __shared__ uint4 sR[4][64];   // 4 KB

    int t = threadIdx.x;
    int w = t >> 6, lane = t & 63;
    int quarter = lane >> 4;       // which edge of the quad this lane serves
    int l = lane & 15;             // channel octet: channels 8l..8l+7
    int h = l >> 2;                // head = (8l)>>5
    int n = blockIdx.x * 4 + w;
    if (n >= N_NODES) return;
    int isf32 = *flag;

    int st = starts[n], en = starts[n + 1];
    float f0 = 0.f, f1 = 0.f, f2 = 0.f, f3 = 0.f;
    float f4 = 0.f, f5 = 0.f, f6 = 0.f, f7 = 0.f, wsum = 0.f;

    for (int base = st; base < en; base += 64) {
        int cnt = en - base;
        if (cnt > 64) cnt = 64;
        __builtin_amdgcn_wave_barrier();
        if (lane < cnt) sR[w][lane] = perm4[base + lane];
        __builtin_amdgcn_wave_barrier();
#pragma unroll 4
        for (int jj = 0; jj < cnt; jj += 4) {
            int j = jj + quarter;
            int valid = (j < cnt);
            int jc = valid ? j : jj;
            uint4 r = sR[w][jc];
            int s = (int)r.x;
            unsigned hw = (h & 2) ? r.z : r.y;
            float wt = (h & 1) ? bf_hi(hw) : bf_lo(hw);
            wt = valid ? wt : 0.f;
            uint4 xv = *(const uint4*)(xh + ((size_t)s << 7) + 8 * l);
            f0 += wt * bf_lo(xv.x);
            f1 += wt * bf_hi(xv.x);
            f2 += wt * bf_lo(xv.y);
            f3 += wt * bf_hi(xv.y);
            f4 += wt * bf_lo(xv.z);
            f5 += wt * bf_hi(xv.z);
            f6 += wt * bf_lo(xv.w);
            f7 += wt * bf_hi(xv.w);
            wsum += wt;
        }
    }

    // combine the four quarters (lane bits 4,5 = quarter bits)
    f0 += __shfl_xor(f0, 16); f0 += __shfl_xor(f0, 32);
    f1 += __shfl_xor(f1, 16); f1 += __shfl_xor(f1, 32);
    f2 += __shfl_xor(f2, 16); f2 += __shfl_xor(f2, 32);
    f3 += __shfl_xor(f3, 16); f3 += __shfl_xor(f3, 32);
    f4 += __shfl_xor(f4, 16); f4 += __shfl_xor(f4, 32);
    f5 += __shfl_xor(f5, 16); f5 += __shfl_xor(f5, 32);
    f6 += __shfl_xor(f6, 16); f6 += __shfl_xor(f6, 32);
    f7 += __shfl_xor(f7, 16); f7 += __shfl_xor(f7, 32);
    wsum += __shfl_xor(wsum, 16); wsum += __shfl_xor(wsum, 32);

    float inv = (wsum > 0.f) ? 1.f / wsum : 0.f;
    int cg = 8 * l;
    float v0 = f0 * inv + gat_bias_f[cg];
    float v1 = f1 * inv + gat_bias_f[cg + 1];
    float v2 = f2 * inv + gat_bias_f[cg + 2];
    float v3 = f3 * inv + gat_bias_f[cg + 3];
    float v4 = f4 * inv + gat_bias_f[cg + 4];
    float v5 = f5 * inv + gat_bias_f[cg + 5];
    float v6 = f6 * inv + gat_bias_f[cg + 6];
    float v7 = f7 * inv + gat_bias_f[cg + 7];
    // reduce over 4 heads: head bits live in lane bits 2,3
    v0 += __shfl_xor(v0, 4); v0 += __shfl_xor(v0, 8);
    v1 += __shfl_xor(v1, 4); v1 += __shfl_xor(v1, 8);
    v2 += __shfl_xor(v2, 4); v2 += __shfl_xor(v2, 8);
    v3 += __shfl_xor(v3, 4); v3 += __shfl_xor(v3, 8);
    v4 += __shfl_xor(v4, 4); v4 += __shfl_xor(v4, 8);
    v5 += __shfl_xor(v5, 4); v5 += __shfl_xor(v5, 8);
    v6 += __shfl_xor(v6, 4); v6 += __shfl_xor(v6, 8);
    v7 += __shfl_xor(v7, 4); v7 += __shfl_xor(v7, 8);

    if (lane < 4) {
        int c = 8 * lane;
        float o0 = fmaxf(v0 * 0.25f + bias_f[c],     0.f);
        float o1 = fmaxf(v1 * 0.25f + bias_f[c + 1], 0.f);
        float o2 = fmaxf(v2 * 0.25f + bias_f[c + 2], 0.f);
        float o3 = fmaxf(v3 * 0.25f + bias_f[c + 3], 0.f);
        float o4 = fmaxf(v4 * 0.25f + bias_f[c + 4], 0.f);
        float o5 = fmaxf(v5 * 0.25f + bias_f[c + 5], 0.f);
        float o6 = fmaxf(v6 * 0.25f + bias_f[c + 6], 0.f);
        float o7 = fmaxf(v7 * 0.25f + bias_f[c + 7], 0.f);
        if (isf32) {
            float* op = (float*)out + (size_t)n * C_OUT + c;
            *(float4*)(op)     = make_float4(o0, o1, o2, o3);
            *(float4*)(op + 4) = make_float4(o4, o5, o6, o7);
        } else {
            unsigned p0 = ((unsigned)f2bf_rne(o1) << 16) | f2bf_rne(o0);
            unsigned p1 = ((unsigned)f2bf_rne(o3) << 16) | f2bf_rne(o2);
            unsigned p2 = ((unsigned)f2bf_rne(o5) << 16) | f2bf_rne(o4);
            unsigned p3 = ((unsigned)f2bf_rne(o7) << 16) | f2bf_rne(o6);
            *(uint4*)((unsigned short*)out + (size_t)n * C_OUT + c) =
                make_uint4(p0, p1, p2, p3);
        }
    }
}

// ---------------------------------------------------------------------------
extern "C" void kernel_launch(void* const* d_in, const int* in_sizes, int n_in,
                              void* d_out, int out_size, void* d_ws, size_t ws_size,
                              hipStream_t stream) {
    const void* x         = d_in[0];
    const int*  ei        = (const int*)d_in[1];
    const void* edge_attr = d_in[2];
    const void* W         = d_in[3];
    const void* att_src   = d_in[4];
    const void* att_dst   = d_in[5];
    const void* W_edge    = d_in[6];
    const void* att_edge  = d_in[7];
    const void* gat_bias  = d_in[8];
    const void* bias      = d_in[9];

    char* ws = (char*)d_ws;
    size_t off = 0;
    auto align256 = [](size_t v) { return (v + 255) & ~(size_t)255; };

    unsigned short* xh = (unsigned short*)(ws + off);
    off = align256(off + (size_t)N_NODES * HC * sizeof(unsigned short));  // 25.6 MB
    float* a_src_w = (float*)(ws + off);
    off = align256(off + (size_t)N_NODES * HEADS * sizeof(float));
    float* a_dst_w = (float*)(ws + off);
    off = align256(off + (size_t)N_NODES * HEADS * sizeof(float));
    int* count = (int*)(ws + off);
    off = align256(off + (size_t)N_NODES * sizeof(int));
    int* starts = (int*)(ws + off);
    off = align256(off + (size_t)(N_NODES + 1) * sizeof(int));
    int* rank = (int*)(ws + off);
    off = align256(off + (size_t)N_EDGES * sizeof(int));                  // 6.4 MB
    int* blockSums = (int*)(ws + off);
    off = align256(off + (size_t)SCAN_BLOCKS * sizeof(int));
    uint4* perm4 = (uint4*)(ws + off);
    off = align256(off + (size_t)N_EDGES * sizeof(uint4));                // 25.6 MB
    float* Wa = (float*)(ws + off);
    off = align256(off + 128 * sizeof(float));
    unsigned short* Wc = (unsigned short*)(ws + off);
    off = align256(off + (size_t)IN_CH * HC * sizeof(unsigned short));
    float* att_src_f = (float*)(ws + off);
    off = align256(off + 128 * sizeof(float));
    float* att_dst_f = (float*)(ws + off);
    off = align256(off + 128 * sizeof(float));
    float* gat_bias_f = (float*)(ws + off);
    off = align256(off + 128 * sizeof(float));
    float* bias_f = (float*)(ws + off);
    off = align256(off + 32 * sizeof(float));
    int* dflag = (int*)(ws + off);
    off = align256(off + sizeof(int));
    size_t need = off;

    if (ws_size < need) {
        report_err<<<1, 64, 0, stream>>>((unsigned short*)d_out, 1500.0f);
        return;
    }

    (void)hipGetLastError();

    prep_small<<<PREP_BLOCKS, 256, 0, stream>>>(x, W, att_src, att_dst,
                                                W_edge, att_edge, gat_bias, bias,
                                                dflag, Wc, att_src_f, att_dst_f,
                                                gat_bias_f, bias_f, Wa, count);
    node_gemm<<<NG_BLOCKS, 256, 0, stream>>>(dflag, x, ei, Wc, att_src_f,
                                             att_dst_f, xh, a_src_w, a_dst_w,
                                             count, rank);
    scan_a<<<SCAN_BLOCKS, 256, 0, stream>>>(count, starts, blockSums);
    scan_b<<<1, 128, 0, stream>>>(blockSums);
    scan_c<<<SCAN_BLOCKS, 256, 0, stream>>>(starts, blockSums);
    edge_scatter<<<ES_BLOCKS, 256, 0, stream>>>(dflag, ei, edge_attr,
                                                a_src_w, a_dst_w, Wa,
                                                starts, rank, perm4);
    gather<<<N_NODES / 4, 256, 0, stream>>>(dflag, starts, perm4,
                                            xh, gat_bias_f, bias_f, d_out);

    hipError_t e = hipGetLastError();
    if (e != hipSuccess) {
        report_err<<<1, 64, 0, stream>>>((unsigned short*)d_out,
                                         1000.0f + (float)(int)e);
    }
}